// Round 3
// baseline (149.407 us; speedup 1.0000x reference)
//
#include <hip/hip_runtime.h>
#include <stdint.h>

#define Hs 96
#define Ws 96
#define HW 9216

typedef _Float16 h2 __attribute__((ext_vector_type(2)));
typedef _Float16 f16x8 __attribute__((ext_vector_type(8)));
typedef float f32x4 __attribute__((ext_vector_type(4)));

// nested-fma bilinear: 1 pk_mul + 3 pk_fma (FP contraction)
__device__ __forceinline__ unsigned interp4(h2 w00, h2 w01, h2 w10, h2 w11,
                                            unsigned a, unsigned bq, unsigned c,
                                            unsigned d) {
  h2 r = w10 * __builtin_bit_cast(h2, c) + w11 * __builtin_bit_cast(h2, d);
  r = w01 * __builtin_bit_cast(h2, bq) + r;
  r = w00 * __builtin_bit_cast(h2, a) + r;
  return __builtin_bit_cast(unsigned, r);
}

// ---- kernel 1: fused prep ----
// blk < 2304: NCHW fp32 -> NHWC fp16 transpose (32x-tile per block)
// blk >= 2304: weight fp32 [O][C][9] -> fp16 planes Wg[t*8+c8][o][8ch]
__global__ __launch_bounds__(256) void k_prep(const float* __restrict__ in,
                                              _Float16* __restrict__ cl,
                                              const float* __restrict__ w,
                                              _Float16* __restrict__ wg) {
  __shared__ _Float16 lt[32 * 68];
  int tid = threadIdx.x;
  int blk = blockIdx.x;
  if (blk >= 2304) {
    int i = (blk - 2304) * 256 + tid;        // 0..36863
    int o = i / 576;
    int r = i - o * 576;                     // tap*64 + c
    int t = r >> 6, c = r & 63;
    wg[((size_t)(t * 8 + (c >> 3)) * 64 + o) * 8 + (c & 7)] =
        (_Float16)w[(o * 64 + c) * 9 + t];
    return;
  }
  int xt = blk % 3;
  int rr = blk / 3;
  int y = rr % Hs;
  int b = rr / Hs;
  int x0 = xt * 32;
  {
    int xx = tid & 31, cc = tid >> 5;
    const float* src = in + (size_t)b * 64 * HW + y * Ws + x0 + xx;
#pragma unroll
    for (int i = 0; i < 8; ++i) {
      int c = cc * 8 + i;
      lt[xx * 68 + c] = (_Float16)src[(size_t)c * HW];
    }
  }
  __syncthreads();
  {
    int c4 = tid & 15, pg = tid >> 4;
    _Float16* dst = cl + ((size_t)(b * Hs + y) * Ws + x0) * 64 + c4 * 4;
#pragma unroll
    for (int i = 0; i < 2; ++i) {
      int x = pg * 2 + i;
      *(uint2*)(dst + (size_t)x * 64) = *(const uint2*)(lt + x * 68 + c4 * 4);
    }
  }
}

// ---- kernel 2: fused sampling + implicit GEMM, barrier-free tap loop ----
// Wave wv owns PIXELS [wv*16, wv*16+16) x all 64 output channels.
// Per-tap LDS hand-off is wave-private (same-wave in-order DS queue).
// R2 fix: A (weight) fragments are prefetched ONE TAP AHEAD and reloaded
// AFTER the MFMA cluster. The MFMAs therefore consume A-regs that are older
// than the in-flight next-tap gathers -> compiler emits vmcnt(16), not
// vmcnt(0); gathers stay in flight across the tap (R1 drained them every
// tap -> full-latency serialization, 55us).
__global__ __launch_bounds__(256, 5) void k_fused(
    const _Float16* __restrict__ incl, const float* __restrict__ off,
    const float* __restrict__ msk, const _Float16* __restrict__ wg,
    const float* __restrict__ bias, float* __restrict__ out) {
  __shared__ unsigned preA[576];     // 2,304 B
  __shared__ uint4 preW[576];        // 9,216 B
  __shared__ uint4 Vw[4][16 * 9];    // 9,216 B (per-wave 16px x 8 chunks, pad 9)

  int tid = threadIdx.x;
  int blk = blockIdx.x;
  int b = blk & 7;              // XCD swizzle: image b on XCD b
  int q0 = (blk >> 3) * 64;     // 144 pixel-tiles per image

  // phase pre: per-(pixel,tap) packed corner address + duplicated weights
  for (int i = tid; i < 576; i += 256) {
    int t = i >> 6, p = i & 63;
    int q = q0 + p;
    int qy = (int)(((unsigned)q * 43691u) >> 22);   // q/96 for q<9216
    int qx = q - qy * 96;
    int ty = t / 3, tx = t - ty * 3;
    float dy = off[(size_t)(b * 18 + 2 * t) * HW + q];
    float dx = off[(size_t)(b * 18 + 2 * t + 1) * HW + q];
    float mv = msk[(size_t)(b * 9 + t) * HW + q];
    float yf = (float)(qy - 1 + ty) + dy;
    float xf = (float)(qx - 1 + tx) + dx;
    float y0f = floorf(yf), x0f = floorf(xf);
    float wy = yf - y0f, wx = xf - x0f;
    int y0 = (int)y0f, x0i = (int)x0f;
    int y1 = y0 + 1, x1 = x0i + 1;
    bool yv0 = (y0 >= 0) && (y0 < Hs);
    bool yv1 = (y1 >= 0) && (y1 < Hs);
    bool xv0 = (x0i >= 0) && (x0i < Ws);
    bool xv1 = (x1 >= 0) && (x1 < Ws);
    int y0c = min(max(y0, 0), Hs - 1), y1c = min(max(y1, 0), Hs - 1);
    int x0c = min(max(x0i, 0), Ws - 1), x1c = min(max(x1, 0), Ws - 1);
    float omy = 1.f - wy, omx = 1.f - wx;
    float f00 = omy * omx * mv * ((yv0 && xv0) ? 1.f : 0.f);
    float f01 = omy * wx  * mv * ((yv0 && xv1) ? 1.f : 0.f);
    float f10 = wy  * omx * mv * ((yv1 && xv0) ? 1.f : 0.f);
    float f11 = wy  * wx  * mv * ((yv1 && xv1) ? 1.f : 0.f);
    preA[i] = ((unsigned)(b * HW + y0c * 96 + x0c) * 128u) |
              (unsigned)(x1c - x0c) | ((unsigned)(y1c - y0c) << 1);
    uint4 pw;
    pw.x = __builtin_bit_cast(unsigned, __builtin_amdgcn_cvt_pkrtz(f00, f00));
    pw.y = __builtin_bit_cast(unsigned, __builtin_amdgcn_cvt_pkrtz(f01, f01));
    pw.z = __builtin_bit_cast(unsigned, __builtin_amdgcn_cvt_pkrtz(f10, f10));
    pw.w = __builtin_bit_cast(unsigned, __builtin_amdgcn_cvt_pkrtz(f11, f11));
    preW[i] = pw;
  }
  __syncthreads();   // the ONLY block-wide barrier

  int lane = tid & 63, wv = tid >> 6;
  int n16 = lane & 15, q4 = lane >> 4;
  int grp = lane >> 3, j = lane & 7;    // sampling: 8-lane group <-> pixel
  int wvb = wv * 16;                    // wave's pixel base within tile
  const char* inb = (const char*)incl;
  const uint4* Ag = (const uint4*)wg;   // plane p: Ag[p*64 + m]

  f32x4 acc[4];
#pragma unroll
  for (int mt = 0; mt < 4; ++mt) {
    f32x4 z = {0.f, 0.f, 0.f, 0.f};
    acc[mt] = z;
  }

  uint4 ga[2][4];       // gathers for current tap: 2 pixel-passes x 4 corners
  uint4 a0r[4], a1r[4]; // A-fragments for CURRENT tap (prefetched last iter)

#define ISSUE_GATHERS(T)                                                     \
  _Pragma("unroll") for (int it = 0; it < 2; ++it) {                         \
    int gg = wvb + grp + it * 8;                                             \
    unsigned ax = preA[(T) * 64 + gg];                                       \
    int a00 = (int)(ax & ~127u) + j * 16;                                    \
    int a01 = a00 + ((ax & 1) << 7);                                         \
    int a10 = a00 + ((ax & 2) * 6144);                                       \
    int a11 = a10 + ((ax & 1) << 7);                                         \
    ga[it][0] = *(const uint4*)(inb + a00);                                  \
    ga[it][1] = *(const uint4*)(inb + a01);                                  \
    ga[it][2] = *(const uint4*)(inb + a10);                                  \
    ga[it][3] = *(const uint4*)(inb + a11);                                  \
  }

#define LOAD_AFRAGS(T)                                                      \
  _Pragma("unroll") for (int mt = 0; mt < 4; ++mt) {                        \
    a0r[mt] = Ag[(size_t)(((T) * 8 + q4) * 64 + mt * 16 + n16)];            \
    a1r[mt] = Ag[(size_t)(((T) * 8 + 4 + q4) * 64 + mt * 16 + n16)];        \
  }

  // prologue: tap 0 gathers, then tap 0 A-fragments (A newer than gathers
  // -> interp(0) waits only vmcnt(8))
  ISSUE_GATHERS(0)
  LOAD_AFRAGS(0)

#pragma unroll
  for (int t = 0; t < 9; ++t) {
    // interp tap t (consumes ga; waits vmcnt(8): A(t) may still fly)
    uint4 v0, v1;
#pragma unroll
    for (int it = 0; it < 2; ++it) {
      uint4 pw = preW[t * 64 + wvb + grp + it * 8];
      h2 w00 = __builtin_bit_cast(h2, pw.x);
      h2 w01 = __builtin_bit_cast(h2, pw.y);
      h2 w10 = __builtin_bit_cast(h2, pw.z);
      h2 w11 = __builtin_bit_cast(h2, pw.w);
      uint4 r;
      r.x = interp4(w00, w01, w10, w11, ga[it][0].x, ga[it][1].x, ga[it][2].x, ga[it][3].x);
      r.y = interp4(w00, w01, w10, w11, ga[it][0].y, ga[it][1].y, ga[it][2].y, ga[it][3].y);
      r.z = interp4(w00, w01, w10, w11, ga[it][0].z, ga[it][1].z, ga[it][2].z, ga[it][3].z);
      r.w = interp4(w00, w01, w10, w11, ga[it][0].w, ga[it][1].w, ga[it][2].w, ga[it][3].w);
      if (it == 0) v0 = r; else v1 = r;
    }
    // issue next tap's gathers early (ga regs dead after interp)
    if (t < 8) {
      ISSUE_GATHERS(t + 1)
    }
    // wave-private hand-off: pixel-local rows grp / grp+8, chunk j
    Vw[wv][grp * 9 + j] = v0;
    Vw[wv][(grp + 8) * 9 + j] = v1;
    // B-fragments back from wave-private LDS (in-order DS queue, no barrier)
    uint4 b0q = Vw[wv][n16 * 9 + q4];
    uint4 b1q = Vw[wv][n16 * 9 + 4 + q4];
    // pin pipeline shape: loads above stay above the MFMA cluster
    __builtin_amdgcn_sched_barrier(0);
    // MFMA consumes a0r/a1r loaded LAST iteration -> vmcnt(16): the 16
    // next-tap gathers stay in flight
#pragma unroll
    for (int mt = 0; mt < 4; ++mt) {
      acc[mt] = __builtin_amdgcn_mfma_f32_16x16x32_f16(
          __builtin_bit_cast(f16x8, a0r[mt]), __builtin_bit_cast(f16x8, b0q),
          acc[mt], 0, 0, 0);
      acc[mt] = __builtin_amdgcn_mfma_f32_16x16x32_f16(
          __builtin_bit_cast(f16x8, a1r[mt]), __builtin_bit_cast(f16x8, b1q),
          acc[mt], 0, 0, 0);
    }
    // reload A for next tap AFTER its last use (in-order issue => WAR-safe)
    if (t < 8) {
      LOAD_AFRAGS(t + 1)
    }
  }
#undef ISSUE_GATHERS
#undef LOAD_AFRAGS

  // epilogue: D col = pixel (n16 -> q0 + wv*16 + n16), row = mt*16 + q4*4 + r
  int colq = q0 + wvb + n16;
  float* op = out + (size_t)b * 64 * HW + colq;
#pragma unroll
  for (int mt = 0; mt < 4; ++mt) {
    f32x4 bv = *(const f32x4*)(bias + mt * 16 + q4 * 4);
#pragma unroll
    for (int r = 0; r < 4; ++r)
      op[(size_t)(mt * 16 + q4 * 4 + r) * HW] = acc[mt][r] + bv[r];
  }
}

extern "C" void kernel_launch(void* const* d_in, const int* in_sizes, int n_in,
                              void* d_out, int out_size, void* d_ws, size_t ws_size,
                              hipStream_t stream) {
  const float* input = (const float*)d_in[0];
  const float* offset = (const float*)d_in[1];
  const float* mask = (const float*)d_in[2];
  const float* weight = (const float*)d_in[3];
  const float* bias = (const float*)d_in[4];
  float* out = (float*)d_out;

  _Float16* incl = (_Float16*)d_ws;                              // 9,437,184 B
  _Float16* wg = (_Float16*)((char*)d_ws + 9437184);             // 73,728 B

  k_prep<<<dim3(2448), dim3(256), 0, stream>>>(input, incl, weight, wg);
  k_fused<<<dim3(1152), dim3(256), 0, stream>>>(incl, offset, mask, wg, bias, out);
}

// Round 4
// 101.868 us; speedup vs baseline: 1.4667x; 1.4667x over previous
//
#include <hip/hip_runtime.h>
#include <stdint.h>

#define Hs 96
#define Ws 96
#define HW 9216

typedef _Float16 h2 __attribute__((ext_vector_type(2)));
typedef _Float16 f16x8 __attribute__((ext_vector_type(8)));
typedef float f32x4 __attribute__((ext_vector_type(4)));

// nested-fma bilinear: 1 pk_mul + 3 pk_fma (FP contraction)
__device__ __forceinline__ unsigned interp4(h2 w00, h2 w01, h2 w10, h2 w11,
                                            unsigned a, unsigned bq, unsigned c,
                                            unsigned d) {
  h2 r = w10 * __builtin_bit_cast(h2, c) + w11 * __builtin_bit_cast(h2, d);
  r = w01 * __builtin_bit_cast(h2, bq) + r;
  r = w00 * __builtin_bit_cast(h2, a) + r;
  return __builtin_bit_cast(unsigned, r);
}

// ---- kernel 1: fused prep ----
// blk < 2304: NCHW fp32 -> NHWC fp16 transpose (32x-tile per block)
// blk >= 2304: weight fp32 [O][C][9] -> fp16 planes Wg[t*8+c8][o][8ch]
__global__ __launch_bounds__(256) void k_prep(const float* __restrict__ in,
                                              _Float16* __restrict__ cl,
                                              const float* __restrict__ w,
                                              _Float16* __restrict__ wg) {
  __shared__ _Float16 lt[32 * 68];
  int tid = threadIdx.x;
  int blk = blockIdx.x;
  if (blk >= 2304) {
    int i = (blk - 2304) * 256 + tid;        // 0..36863
    int o = i / 576;
    int r = i - o * 576;                     // tap*64 + c
    int t = r >> 6, c = r & 63;
    wg[((size_t)(t * 8 + (c >> 3)) * 64 + o) * 8 + (c & 7)] =
        (_Float16)w[(o * 64 + c) * 9 + t];
    return;
  }
  int xt = blk % 3;
  int rr = blk / 3;
  int y = rr % Hs;
  int b = rr / Hs;
  int x0 = xt * 32;
  {
    int xx = tid & 31, cc = tid >> 5;
    const float* src = in + (size_t)b * 64 * HW + y * Ws + x0 + xx;
#pragma unroll
    for (int i = 0; i < 8; ++i) {
      int c = cc * 8 + i;
      lt[xx * 68 + c] = (_Float16)src[(size_t)c * HW];
    }
  }
  __syncthreads();
  {
    int c4 = tid & 15, pg = tid >> 4;
    _Float16* dst = cl + ((size_t)(b * Hs + y) * Ws + x0) * 64 + c4 * 4;
#pragma unroll
    for (int i = 0; i < 2; ++i) {
      int x = pg * 2 + i;
      *(uint2*)(dst + (size_t)x * 64) = *(const uint2*)(lt + x * 68 + c4 * 4);
    }
  }
}

// ---- kernel 2: fused sampling + implicit GEMM, drain-free tap pipeline ----
// (REVERT to the measured-100.35us lockstep structure: R1/R2's wave-private
// rewrites regressed to 55/74us — 4x A-fragment traffic + register spills
// [WRITE_SIZE 47->118MB = scratch]. In THIS form, at each __syncthreads only
// the 2 coalesced A-loads are outstanding (cheap drain) and the 16 gathers
// issued after the barrier fly across the MFMA cluster, which consumes LDS +
// already-arrived regs — no vmcnt(0) stall. Measured k_fused ~25us.)
// Block: 256 threads, 64 pixels. Grid: 1152 = 8 images (blk&7) x 144 tiles.
// R3 delta: LDS-transposed epilogue — stage biased 64x64 f32 tile in LDS
// (reusing dead Vb) and store 128B-full-line dwordx4 per lane instead of
// 16 scalar 64B-segment stores.
__global__ __launch_bounds__(256, 5) void k_fused(
    const _Float16* __restrict__ incl, const float* __restrict__ off,
    const float* __restrict__ msk, const _Float16* __restrict__ wg,
    const float* __restrict__ bias, float* __restrict__ out) {
  __shared__ unsigned preA[576];     // 2,304 B
  __shared__ uint4 preW[576];        // 9,216 B (4 pre-duplicated h2 weights)
  __shared__ uint4 Vb[2][64 * 9];    // 18,432 B (9 uint4 = 144 B per pixel)

  int tid = threadIdx.x;
  int blk = blockIdx.x;
  int b = blk & 7;              // XCD swizzle: image b on XCD b
  int q0 = (blk >> 3) * 64;     // 144 pixel-tiles per image

  // phase pre: per-(pixel,tap) packed corner address + duplicated weights
  for (int i = tid; i < 576; i += 256) {
    int t = i >> 6, p = i & 63;
    int q = q0 + p;
    int qy = (int)(((unsigned)q * 43691u) >> 22);   // q/96 for q<9216
    int qx = q - qy * 96;
    int ty = t / 3, tx = t - ty * 3;
    float dy = off[(size_t)(b * 18 + 2 * t) * HW + q];
    float dx = off[(size_t)(b * 18 + 2 * t + 1) * HW + q];
    float mv = msk[(size_t)(b * 9 + t) * HW + q];
    float yf = (float)(qy - 1 + ty) + dy;
    float xf = (float)(qx - 1 + tx) + dx;
    float y0f = floorf(yf), x0f = floorf(xf);
    float wy = yf - y0f, wx = xf - x0f;
    int y0 = (int)y0f, x0i = (int)x0f;
    int y1 = y0 + 1, x1 = x0i + 1;
    bool yv0 = (y0 >= 0) && (y0 < Hs);
    bool yv1 = (y1 >= 0) && (y1 < Hs);
    bool xv0 = (x0i >= 0) && (x0i < Ws);
    bool xv1 = (x1 >= 0) && (x1 < Ws);
    int y0c = min(max(y0, 0), Hs - 1), y1c = min(max(y1, 0), Hs - 1);
    int x0c = min(max(x0i, 0), Ws - 1), x1c = min(max(x1, 0), Ws - 1);
    float omy = 1.f - wy, omx = 1.f - wx;
    float f00 = omy * omx * mv * ((yv0 && xv0) ? 1.f : 0.f);
    float f01 = omy * wx  * mv * ((yv0 && xv1) ? 1.f : 0.f);
    float f10 = wy  * omx * mv * ((yv1 && xv0) ? 1.f : 0.f);
    float f11 = wy  * wx  * mv * ((yv1 && xv1) ? 1.f : 0.f);
    preA[i] = ((unsigned)(b * HW + y0c * 96 + x0c) * 128u) |
              (unsigned)(x1c - x0c) | ((unsigned)(y1c - y0c) << 1);
    uint4 pw;
    pw.x = __builtin_bit_cast(unsigned, __builtin_amdgcn_cvt_pkrtz(f00, f00));
    pw.y = __builtin_bit_cast(unsigned, __builtin_amdgcn_cvt_pkrtz(f01, f01));
    pw.z = __builtin_bit_cast(unsigned, __builtin_amdgcn_cvt_pkrtz(f10, f10));
    pw.w = __builtin_bit_cast(unsigned, __builtin_amdgcn_cvt_pkrtz(f11, f11));
    preW[i] = pw;
  }
  __syncthreads();

  int j = tid & 7;
  int g = tid >> 3;            // 0..31 (sampling group)
  int lane = tid & 63, wv = tid >> 6;
  int n16 = lane & 15, q4 = lane >> 4;
  const char* inb = (const char*)incl;
  const uint4* Ag = (const uint4*)wg;   // plane p: Ag[p*64 + m]
  int arow = wv * 16 + n16;             // A-operand m index for this lane

  f32x4 acc[4];
#pragma unroll
  for (int pg = 0; pg < 4; ++pg) {
    f32x4 z = {0.f, 0.f, 0.f, 0.f};
    acc[pg] = z;
  }

  uint4 ga[2][4];     // gathers for current tap: 2 pixel-subgroups x 4 corners
  uint4 afn0, afn1;   // prefetched A-fragments (next tap)

#define ISSUE_GATHERS(T)                                                     \
  _Pragma("unroll") for (int it = 0; it < 2; ++it) {                         \
    int gg = g + it * 32;                                                    \
    unsigned ax = preA[(T) * 64 + gg];                                       \
    int a00 = (int)(ax & ~127u) + j * 16;                                    \
    int a01 = a00 + ((ax & 1) << 7);                                         \
    int a10 = a00 + ((ax & 2) * 6144);                                       \
    int a11 = a10 + ((ax & 1) << 7);                                         \
    ga[it][0] = *(const uint4*)(inb + a00);                                  \
    ga[it][1] = *(const uint4*)(inb + a01);                                  \
    ga[it][2] = *(const uint4*)(inb + a10);                                  \
    ga[it][3] = *(const uint4*)(inb + a11);                                  \
  }

  // prologue: tap 0 gathers + tap 0 A-fragments
  ISSUE_GATHERS(0)
  afn0 = Ag[(size_t)((0 + q4) * 64 + arow)];
  afn1 = Ag[(size_t)((4 + q4) * 64 + arow)];

#pragma unroll
  for (int t = 0; t < 9; ++t) {
    int buf = t & 1;
    // interp tap t (consumes ga; hw waits its vmcnt here)
    uint4 v0, v1;
#pragma unroll
    for (int it = 0; it < 2; ++it) {
      int gg = g + it * 32;
      uint4 pw = preW[t * 64 + gg];
      h2 w00 = __builtin_bit_cast(h2, pw.x);
      h2 w01 = __builtin_bit_cast(h2, pw.y);
      h2 w10 = __builtin_bit_cast(h2, pw.z);
      h2 w11 = __builtin_bit_cast(h2, pw.w);
      uint4 r;
      r.x = interp4(w00, w01, w10, w11, ga[it][0].x, ga[it][1].x, ga[it][2].x, ga[it][3].x);
      r.y = interp4(w00, w01, w10, w11, ga[it][0].y, ga[it][1].y, ga[it][2].y, ga[it][3].y);
      r.z = interp4(w00, w01, w10, w11, ga[it][0].z, ga[it][1].z, ga[it][2].z, ga[it][3].z);
      r.w = interp4(w00, w01, w10, w11, ga[it][0].w, ga[it][1].w, ga[it][2].w, ga[it][3].w);
      if (it == 0) v0 = r; else v1 = r;
    }
    uint4 afc0 = afn0, afc1 = afn1;
    Vb[buf][g * 9 + j] = v0;
    Vb[buf][(g + 32) * 9 + j] = v1;
    __syncthreads();   // vm queue ~empty here -> drain is cheap
    if (t < 8) {
      // issue next tap's loads; consumed before the NEXT barrier
      ISSUE_GATHERS(t + 1)
      afn0 = Ag[(size_t)(((t + 1) * 8 + q4) * 64 + arow)];
      afn1 = Ag[(size_t)(((t + 1) * 8 + 4 + q4) * 64 + arow)];
    }
    // MFMA on tap t: wave wv covers m in [wv*16, wv*16+16), all 64 pixels
#pragma unroll
    for (int pg = 0; pg < 4; ++pg) {
      f16x8 b0 = __builtin_bit_cast(f16x8, Vb[buf][(pg * 16 + n16) * 9 + q4]);
      f16x8 b1 = __builtin_bit_cast(f16x8, Vb[buf][(pg * 16 + n16) * 9 + 4 + q4]);
      acc[pg] = __builtin_amdgcn_mfma_f32_16x16x32_f16(
          __builtin_bit_cast(f16x8, afc0), b0, acc[pg], 0, 0, 0);
      acc[pg] = __builtin_amdgcn_mfma_f32_16x16x32_f16(
          __builtin_bit_cast(f16x8, afc1), b1, acc[pg], 0, 0, 0);
    }
  }
#undef ISSUE_GATHERS

  // ---- epilogue (R3 delta): LDS-transposed, 128B-line-coalesced stores ----
  // D fragment: col = pixel n16 (local c = pg*16+n16), row m = wv*16+q4*4+r.
  // Stage biased values into Lep[64 rows][stride 68 floats] (reuses Vb,
  // 17,408B <= 18,432B; stride 68 -> 16B-aligned rows, 2-way-free banks),
  // then each thread stores 4x dwordx4; each wave-instr covers 8 rows x
  // 128B fully-aligned lines (q0*4B is 256B-aligned).
  __syncthreads();                 // all Vb reads of tap 8 done
  float* Lep = (float*)Vb;
  int m0 = wv * 16 + q4 * 4;
  float bv[4];
#pragma unroll
  for (int r = 0; r < 4; ++r) bv[r] = bias[m0 + r];
#pragma unroll
  for (int pg = 0; pg < 4; ++pg) {
    int c = pg * 16 + n16;
#pragma unroll
    for (int r = 0; r < 4; ++r)
      Lep[(m0 + r) * 68 + c] = acc[pg][r] + bv[r];
  }
  __syncthreads();
  {
    int rr = tid >> 3;           // 0..31
    int l8 = tid & 7;            // 0..7
    float* ob = out + (size_t)b * 64 * HW + q0;
#pragma unroll
    for (int p = 0; p < 4; ++p) {
      int row = rr + 32 * (p & 1);
      int colf = l8 * 4 + 32 * (p >> 1);
      f32x4 v = *(const f32x4*)(Lep + row * 68 + colf);
      *(f32x4*)(ob + (size_t)row * HW + colf) = v;
    }
  }
}

extern "C" void kernel_launch(void* const* d_in, const int* in_sizes, int n_in,
                              void* d_out, int out_size, void* d_ws, size_t ws_size,
                              hipStream_t stream) {
  const float* input = (const float*)d_in[0];
  const float* offset = (const float*)d_in[1];
  const float* mask = (const float*)d_in[2];
  const float* weight = (const float*)d_in[3];
  const float* bias = (const float*)d_in[4];
  float* out = (float*)d_out;

  _Float16* incl = (_Float16*)d_ws;                              // 9,437,184 B
  _Float16* wg = (_Float16*)((char*)d_ws + 9437184);             // 73,728 B

  k_prep<<<dim3(2448), dim3(256), 0, stream>>>(input, incl, weight, wg);
  k_fused<<<dim3(1152), dim3(256), 0, stream>>>(incl, offset, mask, wg, bias, out);
}

// Round 5
// 100.452 us; speedup vs baseline: 1.4874x; 1.0141x over previous
//
#include <hip/hip_runtime.h>
#include <stdint.h>

#define Hs 96
#define Ws 96
#define HW 9216

typedef _Float16 h2 __attribute__((ext_vector_type(2)));
typedef _Float16 f16x8 __attribute__((ext_vector_type(8)));
typedef float f32x4 __attribute__((ext_vector_type(4)));

// nested-fma bilinear: 1 pk_mul + 3 pk_fma (FP contraction)
__device__ __forceinline__ unsigned interp4(h2 w00, h2 w01, h2 w10, h2 w11,
                                            unsigned a, unsigned bq, unsigned c,
                                            unsigned d) {
  h2 r = w10 * __builtin_bit_cast(h2, c) + w11 * __builtin_bit_cast(h2, d);
  r = w01 * __builtin_bit_cast(h2, bq) + r;
  r = w00 * __builtin_bit_cast(h2, a) + r;
  return __builtin_bit_cast(unsigned, r);
}

// ---- kernel 1: fused prep ----
// blk < 2304: NCHW fp32 -> NHWC fp16 transpose (32x-tile per block)
// blk >= 2304: weight fp32 [O][C][9] -> fp16 planes Wg[t*8+c8][o][8ch]
__global__ __launch_bounds__(256) void k_prep(const float* __restrict__ in,
                                              _Float16* __restrict__ cl,
                                              const float* __restrict__ w,
                                              _Float16* __restrict__ wg) {
  __shared__ _Float16 lt[32 * 68];
  int tid = threadIdx.x;
  int blk = blockIdx.x;
  if (blk >= 2304) {
    int i = (blk - 2304) * 256 + tid;        // 0..36863
    int o = i / 576;
    int r = i - o * 576;                     // tap*64 + c
    int t = r >> 6, c = r & 63;
    wg[((size_t)(t * 8 + (c >> 3)) * 64 + o) * 8 + (c & 7)] =
        (_Float16)w[(o * 64 + c) * 9 + t];
    return;
  }
  int xt = blk % 3;
  int rr = blk / 3;
  int y = rr % Hs;
  int b = rr / Hs;
  int x0 = xt * 32;
  {
    int xx = tid & 31, cc = tid >> 5;
    const float* src = in + (size_t)b * 64 * HW + y * Ws + x0 + xx;
#pragma unroll
    for (int i = 0; i < 8; ++i) {
      int c = cc * 8 + i;
      lt[xx * 68 + c] = (_Float16)src[(size_t)c * HW];
    }
  }
  __syncthreads();
  {
    int c4 = tid & 15, pg = tid >> 4;
    _Float16* dst = cl + ((size_t)(b * Hs + y) * Ws + x0) * 64 + c4 * 4;
#pragma unroll
    for (int i = 0; i < 2; ++i) {
      int x = pg * 2 + i;
      *(uint2*)(dst + (size_t)x * 64) = *(const uint2*)(lt + x * 68 + c4 * 4);
    }
  }
}

// ---- kernel 2: fused sampling + implicit GEMM, cross-barrier pipeline ----
// Lockstep structure (measured ~25us k_fused): 256 thr / 64 px / tap loop
// with per-tap LDS hand-off. R4 delta (T4-lite): next-tap gathers + A-frags
// are issued BEFORE the tap barrier, and __syncthreads is replaced by
// {s_waitcnt lgkmcnt(0); s_barrier} so the 10 VMEM ops stay IN FLIGHT
// across the barrier. __syncthreads' implicit vmcnt(0) was limiting the
// gather-latency hiding window to one MFMA cluster (~150cyc) vs ~250cyc
// L2 latency. Now the window = barrier + 8 ds_read_b128 + 8 MFMA.
// vmcnt never drains to 0 inside the loop.
__global__ __launch_bounds__(256, 5) void k_fused(
    const _Float16* __restrict__ incl, const float* __restrict__ off,
    const float* __restrict__ msk, const _Float16* __restrict__ wg,
    const float* __restrict__ bias, float* __restrict__ out) {
  __shared__ unsigned preA[576];     // 2,304 B
  __shared__ uint4 preW[576];        // 9,216 B (4 pre-duplicated h2 weights)
  __shared__ uint4 Vb[2][64 * 9];    // 18,432 B (9 uint4 = 144 B per pixel)

  int tid = threadIdx.x;
  int blk = blockIdx.x;
  int b = blk & 7;              // XCD swizzle: image b on XCD b
  int q0 = (blk >> 3) * 64;     // 144 pixel-tiles per image

  // phase pre: per-(pixel,tap) packed corner address + duplicated weights
  for (int i = tid; i < 576; i += 256) {
    int t = i >> 6, p = i & 63;
    int q = q0 + p;
    int qy = (int)(((unsigned)q * 43691u) >> 22);   // q/96 for q<9216
    int qx = q - qy * 96;
    int ty = t / 3, tx = t - ty * 3;
    float dy = off[(size_t)(b * 18 + 2 * t) * HW + q];
    float dx = off[(size_t)(b * 18 + 2 * t + 1) * HW + q];
    float mv = msk[(size_t)(b * 9 + t) * HW + q];
    float yf = (float)(qy - 1 + ty) + dy;
    float xf = (float)(qx - 1 + tx) + dx;
    float y0f = floorf(yf), x0f = floorf(xf);
    float wy = yf - y0f, wx = xf - x0f;
    int y0 = (int)y0f, x0i = (int)x0f;
    int y1 = y0 + 1, x1 = x0i + 1;
    bool yv0 = (y0 >= 0) && (y0 < Hs);
    bool yv1 = (y1 >= 0) && (y1 < Hs);
    bool xv0 = (x0i >= 0) && (x0i < Ws);
    bool xv1 = (x1 >= 0) && (x1 < Ws);
    int y0c = min(max(y0, 0), Hs - 1), y1c = min(max(y1, 0), Hs - 1);
    int x0c = min(max(x0i, 0), Ws - 1), x1c = min(max(x1, 0), Ws - 1);
    float omy = 1.f - wy, omx = 1.f - wx;
    float f00 = omy * omx * mv * ((yv0 && xv0) ? 1.f : 0.f);
    float f01 = omy * wx  * mv * ((yv0 && xv1) ? 1.f : 0.f);
    float f10 = wy  * omx * mv * ((yv1 && xv0) ? 1.f : 0.f);
    float f11 = wy  * wx  * mv * ((yv1 && xv1) ? 1.f : 0.f);
    preA[i] = ((unsigned)(b * HW + y0c * 96 + x0c) * 128u) |
              (unsigned)(x1c - x0c) | ((unsigned)(y1c - y0c) << 1);
    uint4 pw;
    pw.x = __builtin_bit_cast(unsigned, __builtin_amdgcn_cvt_pkrtz(f00, f00));
    pw.y = __builtin_bit_cast(unsigned, __builtin_amdgcn_cvt_pkrtz(f01, f01));
    pw.z = __builtin_bit_cast(unsigned, __builtin_amdgcn_cvt_pkrtz(f10, f10));
    pw.w = __builtin_bit_cast(unsigned, __builtin_amdgcn_cvt_pkrtz(f11, f11));
    preW[i] = pw;
  }
  __syncthreads();

  int j = tid & 7;
  int g = tid >> 3;            // 0..31 (sampling group)
  int lane = tid & 63, wv = tid >> 6;
  int n16 = lane & 15, q4 = lane >> 4;
  const char* inb = (const char*)incl;
  const uint4* Ag = (const uint4*)wg;   // plane p: Ag[p*64 + m]
  int arow = wv * 16 + n16;             // A-operand m index for this lane

  f32x4 acc[4];
#pragma unroll
  for (int pg = 0; pg < 4; ++pg) {
    f32x4 z = {0.f, 0.f, 0.f, 0.f};
    acc[pg] = z;
  }

  uint4 ga[2][4];     // gathers for current tap: 2 pixel-subgroups x 4 corners
  uint4 afn0, afn1;   // prefetched A-fragments (next tap)

#define ISSUE_GATHERS(T)                                                     \
  _Pragma("unroll") for (int it = 0; it < 2; ++it) {                         \
    int gg = g + it * 32;                                                    \
    unsigned ax = preA[(T) * 64 + gg];                                       \
    int a00 = (int)(ax & ~127u) + j * 16;                                    \
    int a01 = a00 + ((ax & 1) << 7);                                         \
    int a10 = a00 + ((ax & 2) * 6144);                                       \
    int a11 = a10 + ((ax & 1) << 7);                                         \
    ga[it][0] = *(const uint4*)(inb + a00);                                  \
    ga[it][1] = *(const uint4*)(inb + a01);                                  \
    ga[it][2] = *(const uint4*)(inb + a10);                                  \
    ga[it][3] = *(const uint4*)(inb + a11);                                  \
  }

  // prologue: tap 0 gathers + tap 0 A-fragments
  ISSUE_GATHERS(0)
  afn0 = Ag[(size_t)((0 + q4) * 64 + arow)];
  afn1 = Ag[(size_t)((4 + q4) * 64 + arow)];

#pragma unroll
  for (int t = 0; t < 9; ++t) {
    int buf = t & 1;
    // interp tap t (consumes ga; waits fine-grained vmcnt, A(t) may fly)
    uint4 v0, v1;
#pragma unroll
    for (int it = 0; it < 2; ++it) {
      int gg = g + it * 32;
      uint4 pw = preW[t * 64 + gg];
      h2 w00 = __builtin_bit_cast(h2, pw.x);
      h2 w01 = __builtin_bit_cast(h2, pw.y);
      h2 w10 = __builtin_bit_cast(h2, pw.z);
      h2 w11 = __builtin_bit_cast(h2, pw.w);
      uint4 r;
      r.x = interp4(w00, w01, w10, w11, ga[it][0].x, ga[it][1].x, ga[it][2].x, ga[it][3].x);
      r.y = interp4(w00, w01, w10, w11, ga[it][0].y, ga[it][1].y, ga[it][2].y, ga[it][3].y);
      r.z = interp4(w00, w01, w10, w11, ga[it][0].z, ga[it][1].z, ga[it][2].z, ga[it][3].z);
      r.w = interp4(w00, w01, w10, w11, ga[it][0].w, ga[it][1].w, ga[it][2].w, ga[it][3].w);
      if (it == 0) v0 = r; else v1 = r;
    }
    uint4 afc0 = afn0, afc1 = afn1;
    Vb[buf][g * 9 + j] = v0;
    Vb[buf][(g + 32) * 9 + j] = v1;
    // R4: issue next tap's loads BEFORE the barrier; they stay in flight
    // across it (no vmcnt in the barrier below).
    if (t < 8) {
      ISSUE_GATHERS(t + 1)
      afn0 = Ag[(size_t)(((t + 1) * 8 + q4) * 64 + arow)];
      afn1 = Ag[(size_t)(((t + 1) * 8 + 4 + q4) * 64 + arow)];
    }
    // ds_writes visible to other waves, then raw barrier (NO vmcnt drain —
    // __syncthreads would wait vmcnt(0) and kill the gather pipeline).
    asm volatile("s_waitcnt lgkmcnt(0)" ::: "memory");
    __builtin_amdgcn_s_barrier();
    __builtin_amdgcn_sched_barrier(0);   // keep ds_reads below the barrier
    // MFMA on tap t: consumes LDS (lgkm auto-waits) + A(t) regs
    // (vmcnt(10): all of G(t+1)+A(t+1) remain outstanding)
#pragma unroll
    for (int pg = 0; pg < 4; ++pg) {
      f16x8 b0 = __builtin_bit_cast(f16x8, Vb[buf][(pg * 16 + n16) * 9 + q4]);
      f16x8 b1 = __builtin_bit_cast(f16x8, Vb[buf][(pg * 16 + n16) * 9 + 4 + q4]);
      acc[pg] = __builtin_amdgcn_mfma_f32_16x16x32_f16(
          __builtin_bit_cast(f16x8, afc0), b0, acc[pg], 0, 0, 0);
      acc[pg] = __builtin_amdgcn_mfma_f32_16x16x32_f16(
          __builtin_bit_cast(f16x8, afc1), b1, acc[pg], 0, 0, 0);
    }
  }
#undef ISSUE_GATHERS

  // ---- epilogue: LDS-transposed, 128B-line-coalesced stores (R3) ----
  __syncthreads();                 // all Vb reads of tap 8 done (queue empty)
  float* Lep = (float*)Vb;
  int m0 = wv * 16 + q4 * 4;
  float bv[4];
#pragma unroll
  for (int r = 0; r < 4; ++r) bv[r] = bias[m0 + r];
#pragma unroll
  for (int pg = 0; pg < 4; ++pg) {
    int c = pg * 16 + n16;
#pragma unroll
    for (int r = 0; r < 4; ++r)
      Lep[(m0 + r) * 68 + c] = acc[pg][r] + bv[r];
  }
  __syncthreads();
  {
    int rr = tid >> 3;           // 0..31
    int l8 = tid & 7;            // 0..7
    float* ob = out + (size_t)b * 64 * HW + q0;
#pragma unroll
    for (int p = 0; p < 4; ++p) {
      int row = rr + 32 * (p & 1);
      int colf = l8 * 4 + 32 * (p >> 1);
      f32x4 v = *(const f32x4*)(Lep + row * 68 + colf);
      *(f32x4*)(ob + (size_t)row * HW + colf) = v;
    }
  }
}

extern "C" void kernel_launch(void* const* d_in, const int* in_sizes, int n_in,
                              void* d_out, int out_size, void* d_ws, size_t ws_size,
                              hipStream_t stream) {
  const float* input = (const float*)d_in[0];
  const float* offset = (const float*)d_in[1];
  const float* mask = (const float*)d_in[2];
  const float* weight = (const float*)d_in[3];
  const float* bias = (const float*)d_in[4];
  float* out = (float*)d_out;

  _Float16* incl = (_Float16*)d_ws;                              // 9,437,184 B
  _Float16* wg = (_Float16*)((char*)d_ws + 9437184);             // 73,728 B

  k_prep<<<dim3(2448), dim3(256), 0, stream>>>(input, incl, weight, wg);
  k_fused<<<dim3(1152), dim3(256), 0, stream>>>(incl, offset, mask, wg, bias, out);
}

// Round 9
// 100.167 us; speedup vs baseline: 1.4916x; 1.0028x over previous
//
#include <hip/hip_runtime.h>
#include <stdint.h>

#define Hs 96
#define Ws 96
#define HW 9216

typedef _Float16 h2 __attribute__((ext_vector_type(2)));
typedef _Float16 f16x8 __attribute__((ext_vector_type(8)));
typedef float f32x4 __attribute__((ext_vector_type(4)));

// nested-fma bilinear: 1 pk_mul + 3 pk_fma (FP contraction)
__device__ __forceinline__ unsigned interp4(h2 w00, h2 w01, h2 w10, h2 w11,
                                            unsigned a, unsigned bq, unsigned c,
                                            unsigned d) {
  h2 r = w10 * __builtin_bit_cast(h2, c) + w11 * __builtin_bit_cast(h2, d);
  r = w01 * __builtin_bit_cast(h2, bq) + r;
  r = w00 * __builtin_bit_cast(h2, a) + r;
  return __builtin_bit_cast(unsigned, r);
}

// ---- kernel 1: fused prep (R8: row-wide float4 version) ----
// blk < 768: one block per (b,y) image row. Reads 64ch x 96x fp32 via
// float4 (384B-contiguous per channel row), LDS-transposes at stride 72
// (144B rows -> 16B-aligned uint4 slots), writes NHWC fp16 as 3 fully-
// coalesced dwordx4/thread (wave-instr = 8px x 128B contiguous).
// blk >= 768: weight fp32 [O][C][9] -> fp16 planes Wg[t*8+c8][o][8ch],
// exactly 1 elem/thread (144 blocks x 256 = 36,864).
__global__ __launch_bounds__(256) void k_prep(const float* __restrict__ in,
                                              _Float16* __restrict__ cl,
                                              const float* __restrict__ w,
                                              _Float16* __restrict__ wg) {
  __shared__ _Float16 lt[96 * 72];   // 13,824 B; row = x, stride 72 fp16
  int tid = threadIdx.x;
  int blk = blockIdx.x;
  if (blk >= 768) {
    int i = (blk - 768) * 256 + tid;         // 0..36863
    int o = i / 576;
    int r = i - o * 576;                     // tap*64 + c
    int t = r >> 6, c = r & 63;
    wg[((size_t)(t * 8 + (c >> 3)) * 64 + o) * 8 + (c & 7)] =
        (_Float16)w[(o * 64 + c) * 9 + t];
    return;
  }
  int y = blk % Hs;
  int b = blk / Hs;
  {
    int c = tid >> 2, q = tid & 3;           // lane group: channel c, quarter q
    const float* src = in + (size_t)(b * 64 + c) * HW + y * Ws;
#pragma unroll
    for (int i = 0; i < 6; ++i) {
      int f4 = q + 4 * i;                    // 0..23 (float4 index in row)
      f32x4 v = *(const f32x4*)(src + f4 * 4);
#pragma unroll
      for (int k = 0; k < 4; ++k)
        lt[(f4 * 4 + k) * 72 + c] = (_Float16)v[k];
    }
  }
  __syncthreads();
  {
    _Float16* dst = cl + (size_t)(b * Hs + y) * Ws * 64;
#pragma unroll
    for (int i = 0; i < 3; ++i) {
      int u = i * 256 + tid;                 // 0..767 (uint4 index in row)
      int px = u >> 3, wd = u & 7;
      *(uint4*)(dst + px * 64 + wd * 8) = *(const uint4*)(lt + px * 72 + wd * 8);
    }
  }
}

// ---- kernel 2: fused sampling + implicit GEMM, cross-barrier pipeline ----
// Measured-good lockstep structure (100.45us total, refcheck-passed):
// 256 thr / 64 px / tap loop, per-tap LDS hand-off. Next-tap gathers +
// A-frags issued BEFORE the tap barrier; barrier = {lgkmcnt(0); s_barrier}
// (no vmcnt drain) so the 10 VMEM ops stay in flight across it.
// NOTE R5/R8 lesson: single-kernel coop merge (grid.sync + threadfence)
// FAILED correctness on gfx950 — cross-XCD visibility of ws data through
// plain stores + agent fences is NOT reliable. Keep the two-kernel split;
// the kernel-boundary release/acquire is the only proven publish path.
__global__ __launch_bounds__(256, 5) void k_fused(
    const _Float16* __restrict__ incl, const float* __restrict__ off,
    const float* __restrict__ msk, const _Float16* __restrict__ wg,
    const float* __restrict__ bias, float* __restrict__ out) {
  __shared__ unsigned preA[576];     // 2,304 B
  __shared__ uint4 preW[576];        // 9,216 B (4 pre-duplicated h2 weights)
  __shared__ uint4 Vb[2][64 * 9];    // 18,432 B (9 uint4 = 144 B per pixel)

  int tid = threadIdx.x;
  int blk = blockIdx.x;
  int b = blk & 7;              // XCD swizzle: image b on XCD b
  int q0 = (blk >> 3) * 64;     // 144 pixel-tiles per image

  // phase pre: per-(pixel,tap) packed corner address + duplicated weights
  for (int i = tid; i < 576; i += 256) {
    int t = i >> 6, p = i & 63;
    int q = q0 + p;
    int qy = (int)(((unsigned)q * 43691u) >> 22);   // q/96 for q<9216
    int qx = q - qy * 96;
    int ty = t / 3, tx = t - ty * 3;
    float dy = off[(size_t)(b * 18 + 2 * t) * HW + q];
    float dx = off[(size_t)(b * 18 + 2 * t + 1) * HW + q];
    float mv = msk[(size_t)(b * 9 + t) * HW + q];
    float yf = (float)(qy - 1 + ty) + dy;
    float xf = (float)(qx - 1 + tx) + dx;
    float y0f = floorf(yf), x0f = floorf(xf);
    float wy = yf - y0f, wx = xf - x0f;
    int y0 = (int)y0f, x0i = (int)x0f;
    int y1 = y0 + 1, x1 = x0i + 1;
    bool yv0 = (y0 >= 0) && (y0 < Hs);
    bool yv1 = (y1 >= 0) && (y1 < Hs);
    bool xv0 = (x0i >= 0) && (x0i < Ws);
    bool xv1 = (x1 >= 0) && (x1 < Ws);
    int y0c = min(max(y0, 0), Hs - 1), y1c = min(max(y1, 0), Hs - 1);
    int x0c = min(max(x0i, 0), Ws - 1), x1c = min(max(x1, 0), Ws - 1);
    float omy = 1.f - wy, omx = 1.f - wx;
    float f00 = omy * omx * mv * ((yv0 && xv0) ? 1.f : 0.f);
    float f01 = omy * wx  * mv * ((yv0 && xv1) ? 1.f : 0.f);
    float f10 = wy  * omx * mv * ((yv1 && xv0) ? 1.f : 0.f);
    float f11 = wy  * wx  * mv * ((yv1 && xv1) ? 1.f : 0.f);
    preA[i] = ((unsigned)(b * HW + y0c * 96 + x0c) * 128u) |
              (unsigned)(x1c - x0c) | ((unsigned)(y1c - y0c) << 1);
    uint4 pw;
    pw.x = __builtin_bit_cast(unsigned, __builtin_amdgcn_cvt_pkrtz(f00, f00));
    pw.y = __builtin_bit_cast(unsigned, __builtin_amdgcn_cvt_pkrtz(f01, f01));
    pw.z = __builtin_bit_cast(unsigned, __builtin_amdgcn_cvt_pkrtz(f10, f10));
    pw.w = __builtin_bit_cast(unsigned, __builtin_amdgcn_cvt_pkrtz(f11, f11));
    preW[i] = pw;
  }
  __syncthreads();

  int j = tid & 7;
  int g = tid >> 3;            // 0..31 (sampling group)
  int lane = tid & 63, wv = tid >> 6;
  int n16 = lane & 15, q4 = lane >> 4;
  const char* inb = (const char*)incl;
  const uint4* Ag = (const uint4*)wg;   // plane p: Ag[p*64 + m]
  int arow = wv * 16 + n16;             // A-operand m index for this lane

  f32x4 acc[4];
#pragma unroll
  for (int pg = 0; pg < 4; ++pg) {
    f32x4 z = {0.f, 0.f, 0.f, 0.f};
    acc[pg] = z;
  }

  uint4 ga[2][4];     // gathers for current tap: 2 pixel-subgroups x 4 corners
  uint4 afn0, afn1;   // prefetched A-fragments (next tap)

#define ISSUE_GATHERS(T)                                                     \
  _Pragma("unroll") for (int it = 0; it < 2; ++it) {                         \
    int gg = g + it * 32;                                                    \
    unsigned ax = preA[(T) * 64 + gg];                                       \
    int a00 = (int)(ax & ~127u) + j * 16;                                    \
    int a01 = a00 + ((ax & 1) << 7);                                         \
    int a10 = a00 + ((ax & 2) * 6144);                                       \
    int a11 = a10 + ((ax & 1) << 7);                                         \
    ga[it][0] = *(const uint4*)(inb + a00);                                  \
    ga[it][1] = *(const uint4*)(inb + a01);                                  \
    ga[it][2] = *(const uint4*)(inb + a10);                                  \
    ga[it][3] = *(const uint4*)(inb + a11);                                  \
  }

  // prologue: tap 0 gathers + tap 0 A-fragments
  ISSUE_GATHERS(0)
  afn0 = Ag[(size_t)((0 + q4) * 64 + arow)];
  afn1 = Ag[(size_t)((4 + q4) * 64 + arow)];

#pragma unroll
  for (int t = 0; t < 9; ++t) {
    int buf = t & 1;
    // interp tap t (consumes ga; fine-grained vmcnt, A(t) may still fly)
    uint4 v0, v1;
#pragma unroll
    for (int it = 0; it < 2; ++it) {
      int gg = g + it * 32;
      uint4 pw = preW[t * 64 + gg];
      h2 w00 = __builtin_bit_cast(h2, pw.x);
      h2 w01 = __builtin_bit_cast(h2, pw.y);
      h2 w10 = __builtin_bit_cast(h2, pw.z);
      h2 w11 = __builtin_bit_cast(h2, pw.w);
      uint4 r;
      r.x = interp4(w00, w01, w10, w11, ga[it][0].x, ga[it][1].x, ga[it][2].x, ga[it][3].x);
      r.y = interp4(w00, w01, w10, w11, ga[it][0].y, ga[it][1].y, ga[it][2].y, ga[it][3].y);
      r.z = interp4(w00, w01, w10, w11, ga[it][0].z, ga[it][1].z, ga[it][2].z, ga[it][3].z);
      r.w = interp4(w00, w01, w10, w11, ga[it][0].w, ga[it][1].w, ga[it][2].w, ga[it][3].w);
      if (it == 0) v0 = r; else v1 = r;
    }
    uint4 afc0 = afn0, afc1 = afn1;
    Vb[buf][g * 9 + j] = v0;
    Vb[buf][(g + 32) * 9 + j] = v1;
    // next tap's loads issued BEFORE the barrier; stay in flight across it
    if (t < 8) {
      ISSUE_GATHERS(t + 1)
      afn0 = Ag[(size_t)(((t + 1) * 8 + q4) * 64 + arow)];
      afn1 = Ag[(size_t)(((t + 1) * 8 + 4 + q4) * 64 + arow)];
    }
    // ds_writes visible, then raw barrier (NO vmcnt drain)
    asm volatile("s_waitcnt lgkmcnt(0)" ::: "memory");
    __builtin_amdgcn_s_barrier();
    __builtin_amdgcn_sched_barrier(0);   // keep ds_reads below the barrier
    // MFMA on tap t: wave wv covers m in [wv*16, wv*16+16), all 64 pixels
#pragma unroll
    for (int pg = 0; pg < 4; ++pg) {
      f16x8 b0 = __builtin_bit_cast(f16x8, Vb[buf][(pg * 16 + n16) * 9 + q4]);
      f16x8 b1 = __builtin_bit_cast(f16x8, Vb[buf][(pg * 16 + n16) * 9 + 4 + q4]);
      acc[pg] = __builtin_amdgcn_mfma_f32_16x16x32_f16(
          __builtin_bit_cast(f16x8, afc0), b0, acc[pg], 0, 0, 0);
      acc[pg] = __builtin_amdgcn_mfma_f32_16x16x32_f16(
          __builtin_bit_cast(f16x8, afc1), b1, acc[pg], 0, 0, 0);
    }
  }
#undef ISSUE_GATHERS

  // ---- epilogue: LDS-transposed, 128B-line-coalesced stores ----
  __syncthreads();                 // all Vb reads of tap 8 done
  float* Lep = (float*)Vb;
  int m0 = wv * 16 + q4 * 4;
  float bv[4];
#pragma unroll
  for (int r = 0; r < 4; ++r) bv[r] = bias[m0 + r];
#pragma unroll
  for (int pg = 0; pg < 4; ++pg) {
    int c = pg * 16 + n16;
#pragma unroll
    for (int r = 0; r < 4; ++r)
      Lep[(m0 + r) * 68 + c] = acc[pg][r] + bv[r];
  }
  __syncthreads();
  {
    int rr = tid >> 3;           // 0..31
    int l8 = tid & 7;            // 0..7
    float* ob = out + (size_t)b * 64 * HW + q0;
#pragma unroll
    for (int p = 0; p < 4; ++p) {
      int row = rr + 32 * (p & 1);
      int colf = l8 * 4 + 32 * (p >> 1);
      f32x4 v = *(const f32x4*)(Lep + row * 68 + colf);
      *(f32x4*)(ob + (size_t)row * HW + colf) = v;
    }
  }
}

extern "C" void kernel_launch(void* const* d_in, const int* in_sizes, int n_in,
                              void* d_out, int out_size, void* d_ws, size_t ws_size,
                              hipStream_t stream) {
  const float* input = (const float*)d_in[0];
  const float* offset = (const float*)d_in[1];
  const float* mask = (const float*)d_in[2];
  const float* weight = (const float*)d_in[3];
  const float* bias = (const float*)d_in[4];
  float* out = (float*)d_out;

  _Float16* incl = (_Float16*)d_ws;                              // 9,437,184 B
  _Float16* wg = (_Float16*)((char*)d_ws + 9437184);             // 73,728 B

  k_prep<<<dim3(912), dim3(256), 0, stream>>>(input, incl, weight, wg);
  k_fused<<<dim3(1152), dim3(256), 0, stream>>>(incl, offset, mask, wg, bias, out);
}